// Round 5
// baseline (486.792 us; speedup 1.0000x reference)
//
#include <hip/hip_runtime.h>
#include <stdint.h>

#define NDET 8192
#define ROWCAP 128      // max stored edges per row (j>i). P(overflow) ~ 0 for this data.

// ---------------- ws layout (bytes) ----------------
// 0        float4 boxes[8192]    131072
// 131072   float  area [8192]     32768   (reused as u32 minidx[8192] after k_edges)
// 163840   u32    cnt  [8192]     32768
// 196608   u32    alab [8192]     32768
// 229376   u64    mcg  [8192]     65536
// 294912   u32    cntk [8192]     32768
// 327680   u32    rankk[8192]     32768
// 360448   u32    sched[8192]     32768
// 393216   u16    edges[8192][128] 2097152   (total 2490368 B)

// Extract edge e (compile-time constant after unroll) from the two uint4 regs.
#define EW(e) ((e) < 8 ? (((e) >> 1) == 0 ? pa.x : ((e) >> 1) == 1 ? pa.y : ((e) >> 1) == 2 ? pa.z : pa.w) \
                       : ((((e) - 8) >> 1) == 0 ? pb.x : (((e) - 8) >> 1) == 1 ? pb.y : (((e) - 8) >> 1) == 2 ? pb.z : pb.w))
#define EDGE(e) ((int)((EW(e) >> (((e) & 1) * 16)) & 0xFFFFu))

__global__ __launch_bounds__(256) void k_init(const float4* __restrict__ bb,
    float4* __restrict__ boxes, float* __restrict__ area,
    unsigned long long* __restrict__ mcg, uint32_t* __restrict__ cntk,
    uint32_t* __restrict__ rankk, int32_t* __restrict__ out) {
  #pragma clang fp contract(off)
  int v = blockIdx.x * 256 + threadIdx.x;
  if (v >= NDET) return;
  float4 b = bb[v];
  float x1 = b.x - 0.5f * b.z, y1 = b.y - 0.5f * b.w;
  float x2 = b.x + 0.5f * b.z, y2 = b.y + 0.5f * b.w;
  boxes[v] = make_float4(x1, y1, x2, y2);
  area[v] = (x2 - x1) * (y2 - y1);
  mcg[v] = 0ull; cntk[v] = 0u; rankk[v] = 0u;
  out[v] = 0;                           // output is int32 (bool mask)
}

// One wave handles rows (w) and (8191-w): balanced upper-triangle scan.
__global__ __launch_bounds__(256) void k_edges(const float4* __restrict__ boxes,
    const float* __restrict__ area, uint32_t* __restrict__ cnt,
    uint16_t* __restrict__ edges) {
  #pragma clang fp contract(off)
  int wid  = (blockIdx.x * 256 + threadIdx.x) >> 6;   // 0..4095
  int lane = threadIdx.x & 63;
  for (int half = 0; half < 2; ++half) {
    int r = (half == 0) ? wid : (NDET - 1 - wid);
    float4 bi = boxes[r];
    float   ai = area[r];
    uint16_t* erow = edges + (size_t)r * ROWCAP;
    int cnt_total = 0;
    for (int jc = (r + 1) >> 6; jc < NDET / 64; ++jc) {
      int j = (jc << 6) + lane;
      bool pred = false;
      if (j > r) {
        float4 bj = boxes[j];
        float  aj = area[j];
        float ltx = fmaxf(bi.x, bj.x), lty = fmaxf(bi.y, bj.y);
        float rbx = fminf(bi.z, bj.z), rby = fminf(bi.w, bj.w);
        float iw = fmaxf(rbx - ltx, 0.0f), ih = fmaxf(rby - lty, 0.0f);
        float inter = iw * ih;
        float uni = ai + aj - inter;     // > 0 always (w,h >= 10)
        float iou = inter / uni;         // IEEE div, matches reference
        pred = iou > 0.1f;
      }
      unsigned long long m = __ballot(pred);
      if (pred) {
        int pos = cnt_total + __popcll(m & ((1ull << lane) - 1ull));
        if (pos < ROWCAP) erow[pos] = (uint16_t)j;
      }
      cnt_total += __popcll(m);
    }
    if (lane == 0) cnt[r] = (uint32_t)min(cnt_total, ROWCAP);
  }
}

// Static conflict scheduling: one block per batch of 64 consecutive rows.
// Row r's vertex set = {r} U nbr(r). Row is ready in round k iff it wins the
// claim (min batch-rank) on ALL its vertices among not-yet-scheduled rows.
// Reproduces exactly the order-dependence of the sequential scan, independent
// of label values, so all 128 batches schedule in parallel.
// Also initializes minidx[] (stream-ordered before k_fold1).
__global__ __launch_bounds__(64) void k_sched(const uint16_t* __restrict__ edges,
    const uint32_t* __restrict__ cnt, uint32_t* __restrict__ sched,
    uint32_t* __restrict__ minidx) {
  __shared__ uint32_t claim[NDET];     // 32 KB
  const int t = threadIdx.x;
  const int base = blockIdx.x << 6;
  const int r = base + t;
  minidx[r] = 0xFFFFFFFFu;
  {
    uint4* c4 = reinterpret_cast<uint4*>(claim);
    uint4 ff = make_uint4(0xFFFFFFFFu, 0xFFFFFFFFu, 0xFFFFFFFFu, 0xFFFFFFFFu);
    for (int v = t; v < NDET / 4; v += 64) c4[v] = ff;
  }
  const uint16_t* ep = edges + (size_t)r * ROWCAP;
  uint4 pa = *reinterpret_cast<const uint4*>(ep);
  uint4 pb = *reinterpret_cast<const uint4*>(ep + 8);
  uint32_t deg = cnt[r];
  __syncthreads();

  bool done = (deg == 0u);             // zero-degree rows are exact no-ops
  uint32_t myround = 0u;
  int k = 0;
  while (__ballot(!done)) {
    ++k;                               // k <= 64 (lowest undone rank always wins)
    const uint32_t key = ((uint32_t)(64 - k) << 8) | (uint32_t)t;  // newer round -> smaller key
    if (!done) {
      atomicMin(&claim[r], key);
      #pragma unroll
      for (int e = 0; e < 16; ++e)
        if (e < (int)deg) atomicMin(&claim[EDGE(e)], key);
      for (int e = 16; e < (int)deg; ++e)
        atomicMin(&claim[(int)ep[e]], key);
    }
    __syncthreads();
    if (!done) {
      bool ready = (claim[r] == key);
      #pragma unroll
      for (int e = 0; e < 16; ++e)
        if (e < (int)deg && claim[EDGE(e)] != key) ready = false;
      for (int e = 16; ready && e < (int)deg; ++e)
        if (claim[(int)ep[e]] != key) ready = false;
      if (ready) { myround = (uint32_t)k; done = true; }
    }
    __syncthreads();
  }
  sched[r] = myround;
}

// Single-wave sequential-semantics executor: batches of 64 rows in order,
// within a batch rows execute at their precomputed round (disjoint per round).
__global__ __launch_bounds__(64) void k_scan(const uint16_t* __restrict__ edges,
    const uint32_t* __restrict__ cnt, const uint32_t* __restrict__ sched,
    uint32_t* __restrict__ aout) {
  __shared__ uint16_t a[NDET];         // 16 KB labels
  const int t = threadIdx.x;
  for (int v = t; v < NDET; v += 64) a[v] = (uint16_t)v;
  __syncthreads();

  // prefetch batch 0
  const uint16_t* ep = edges + (size_t)t * ROWCAP;
  uint4 pa = *reinterpret_cast<const uint4*>(ep);
  uint4 pb = *reinterpret_cast<const uint4*>(ep + 8);
  uint32_t deg = cnt[t];
  uint32_t rnd = sched[t];

  for (int b = 0; b < NDET / 64; ++b) {
    const int r = (b << 6) + t;
    uint4 pan = make_uint4(0, 0, 0, 0), pbn = make_uint4(0, 0, 0, 0);
    uint32_t degn = 0u, rndn = 0u;
    if (b < NDET / 64 - 1) {           // prefetch next batch; waits land after rounds
      const uint16_t* en = edges + (size_t)(r + 64) * ROWCAP;
      pan = *reinterpret_cast<const uint4*>(en);
      pbn = *reinterpret_cast<const uint4*>(en + 8);
      degn = cnt[r + 64];
      rndn = sched[r + 64];
    }
    uint32_t k = 1u;
    while (__ballot(rnd >= k)) {
      if (rnd == k) {
        // exact row semantics: prefix-min chain over ascending neighbors
        int cur = (int)a[r];
        #pragma unroll
        for (int e = 0; e < 16; ++e) {
          if (e < (int)deg) {
            int j = EDGE(e);
            int aj = (int)a[j];
            if (aj < cur) cur = aj;
            a[j] = (uint16_t)cur;
          }
        }
        for (int e = 16; e < (int)deg; ++e) {
          int j = (int)edges[(size_t)r * ROWCAP + e];
          int aj = (int)a[j];
          if (aj < cur) cur = aj;
          a[j] = (uint16_t)cur;
        }
        a[r] = (uint16_t)cur;
      }
      __syncthreads();                 // single wave: ~s_waitcnt lgkmcnt(0)
      ++k;
    }
    pa = pan; pb = pbn; deg = degn; rnd = rndn;
  }

  __syncthreads();
  for (int v = t; v < NDET; v += 64) aout[v] = (uint32_t)a[v];
}

// per-label stats: count, min member index, argmax-conf (min-idx tie-break)
__global__ __launch_bounds__(256) void k_fold1(const uint32_t* __restrict__ alab,
    const float* __restrict__ conf, unsigned long long* __restrict__ mcg,
    uint32_t* __restrict__ cntk, uint32_t* __restrict__ minidx) {
  int v = blockIdx.x * 256 + threadIdx.x;
  if (v >= NDET) return;
  uint32_t L = alab[v];
  unsigned long long key = ((unsigned long long)__float_as_uint(conf[v]) << 32)
                         | (unsigned long long)(NDET - 1 - v);
  atomicMax(&mcg[L], key);
  atomicAdd(&cntk[L], 1u);
  atomicMin(&minidx[L], (uint32_t)v);
}

// rank of argmax member within its cluster = #members with smaller index
__global__ __launch_bounds__(256) void k_fold2(const uint32_t* __restrict__ alab,
    const unsigned long long* __restrict__ mcg, uint32_t* __restrict__ rankk) {
  int v = blockIdx.x * 256 + threadIdx.x;
  if (v >= NDET) return;
  uint32_t L = alab[v];
  uint32_t g = (uint32_t)(NDET - 1) - (uint32_t)(mcg[L] & 0xFFFFFFFFull);
  if ((uint32_t)v < g) atomicAdd(&rankk[L], 1u);
}

// Emit one mask bit per PRESENT label value (cntk[L] > 0). No root assumption:
// a label L can be held by vertices even when a[L] != L (one-pass prefix-min
// scan is not a full connected-components pass).
__global__ __launch_bounds__(256) void k_mask(const uint32_t* __restrict__ cntk,
    const uint32_t* __restrict__ minidx, const uint32_t* __restrict__ rankk,
    int32_t* __restrict__ out) {
  int L = blockIdx.x * 256 + threadIdx.x;
  if (L >= NDET) return;
  uint32_t c = cntk[L];
  if (c > 0u) {
    uint32_t idx = (c == 1u) ? minidx[L] : rankk[L];
    out[idx] = 1;                      // idx < NDET always (member index or rank < count)
  }
}

extern "C" void kernel_launch(void* const* d_in, const int* in_sizes, int n_in,
                              void* d_out, int out_size, void* d_ws, size_t ws_size,
                              hipStream_t stream) {
  const float4* bb  = (const float4*)d_in[0];
  const float* conf = (const float*)d_in[1];
  char* ws = (char*)d_ws;
  float4*             boxes  = (float4*)(ws + 0);
  float*              area   = (float*)(ws + 131072);
  uint32_t*           minidx = (uint32_t*)(ws + 131072);  // reuses area (dead after k_edges)
  uint32_t*           cnt    = (uint32_t*)(ws + 163840);
  uint32_t*           alab   = (uint32_t*)(ws + 196608);
  unsigned long long* mcg    = (unsigned long long*)(ws + 229376);
  uint32_t*           cntk   = (uint32_t*)(ws + 294912);
  uint32_t*           rankk  = (uint32_t*)(ws + 327680);
  uint32_t*           sched  = (uint32_t*)(ws + 360448);
  uint16_t*           edges  = (uint16_t*)(ws + 393216);
  int32_t* out = (int32_t*)d_out;

  hipLaunchKernelGGL(k_init,  dim3(NDET / 256), dim3(256), 0, stream,
                     bb, boxes, area, mcg, cntk, rankk, out);
  hipLaunchKernelGGL(k_edges, dim3(1024),       dim3(256), 0, stream,
                     boxes, area, cnt, edges);
  hipLaunchKernelGGL(k_sched, dim3(NDET / 64),  dim3(64),  0, stream,
                     edges, cnt, sched, minidx);
  hipLaunchKernelGGL(k_scan,  dim3(1),          dim3(64),  0, stream,
                     edges, cnt, sched, alab);
  hipLaunchKernelGGL(k_fold1, dim3(NDET / 256), dim3(256), 0, stream,
                     alab, conf, mcg, cntk, minidx);
  hipLaunchKernelGGL(k_fold2, dim3(NDET / 256), dim3(256), 0, stream,
                     alab, mcg, rankk);
  hipLaunchKernelGGL(k_mask,  dim3(NDET / 256), dim3(256), 0, stream,
                     cntk, minidx, rankk, out);
}

// Round 6
// 350.261 us; speedup vs baseline: 1.3898x; 1.3898x over previous
//
#include <hip/hip_runtime.h>
#include <stdint.h>

#define NDET 8192
#define ROWCAP 128      // max stored edges per row (j>i). P(overflow) ~ 0 for this data.
#define BATCH 256
#define NBATCH (NDET / BATCH)

// ---------------- ws layout (bytes) ----------------
// 0        float4 boxes[8192]    131072
// 131072   float  area [8192]     32768   (reused as u32 minidx[8192] after k_edges)
// 163840   u32    cnt  [8192]     32768
// 196608   u32    alab [8192]     32768
// 229376   u64    mcg  [8192]     65536
// 294912   u32    cntk [8192]     32768
// 327680   u32    rankk[8192]     32768
// 360448   u16    sched[8192]     16384
// 376832   int    depth[32]         128
// 393216   u16    edges[8192][128] 2097152   (total 2490368 B)

// Extract edge e (compile-time constant after unroll) from the two uint4 regs.
#define EW(e) ((e) < 8 ? (((e) >> 1) == 0 ? pa.x : ((e) >> 1) == 1 ? pa.y : ((e) >> 1) == 2 ? pa.z : pa.w) \
                       : ((((e) - 8) >> 1) == 0 ? pb.x : (((e) - 8) >> 1) == 1 ? pb.y : (((e) - 8) >> 1) == 2 ? pb.z : pb.w))
#define EDGE(e) ((int)((EW(e) >> (((e) & 1) * 16)) & 0xFFFFu))

__global__ __launch_bounds__(256) void k_init(const float4* __restrict__ bb,
    float4* __restrict__ boxes, float* __restrict__ area,
    unsigned long long* __restrict__ mcg, uint32_t* __restrict__ cntk,
    uint32_t* __restrict__ rankk, int32_t* __restrict__ out) {
  #pragma clang fp contract(off)
  int v = blockIdx.x * 256 + threadIdx.x;
  if (v >= NDET) return;
  float4 b = bb[v];
  float x1 = b.x - 0.5f * b.z, y1 = b.y - 0.5f * b.w;
  float x2 = b.x + 0.5f * b.z, y2 = b.y + 0.5f * b.w;
  boxes[v] = make_float4(x1, y1, x2, y2);
  area[v] = (x2 - x1) * (y2 - y1);
  mcg[v] = 0ull; cntk[v] = 0u; rankk[v] = 0u;
  out[v] = 0;                           // output is int32 (bool mask)
}

// One wave handles rows (w) and (8191-w): balanced upper-triangle scan.
__global__ __launch_bounds__(256) void k_edges(const float4* __restrict__ boxes,
    const float* __restrict__ area, uint32_t* __restrict__ cnt,
    uint16_t* __restrict__ edges) {
  #pragma clang fp contract(off)
  int wid  = (blockIdx.x * 256 + threadIdx.x) >> 6;   // 0..4095
  int lane = threadIdx.x & 63;
  for (int half = 0; half < 2; ++half) {
    int r = (half == 0) ? wid : (NDET - 1 - wid);
    float4 bi = boxes[r];
    float   ai = area[r];
    uint16_t* erow = edges + (size_t)r * ROWCAP;
    int cnt_total = 0;
    for (int jc = (r + 1) >> 6; jc < NDET / 64; ++jc) {
      int j = (jc << 6) + lane;
      bool pred = false;
      if (j > r) {
        float4 bj = boxes[j];
        float  aj = area[j];
        float ltx = fmaxf(bi.x, bj.x), lty = fmaxf(bi.y, bj.y);
        float rbx = fminf(bi.z, bj.z), rby = fminf(bi.w, bj.w);
        float iw = fmaxf(rbx - ltx, 0.0f), ih = fmaxf(rby - lty, 0.0f);
        float inter = iw * ih;
        float uni = ai + aj - inter;     // > 0 always (w,h >= 10)
        float iou = inter / uni;         // IEEE div, matches reference
        pred = iou > 0.1f;
      }
      unsigned long long m = __ballot(pred);
      if (pred) {
        int pos = cnt_total + __popcll(m & ((1ull << lane) - 1ull));
        if (pos < ROWCAP) erow[pos] = (uint16_t)j;
      }
      cnt_total += __popcll(m);
    }
    if (lane == 0) cnt[r] = (uint32_t)min(cnt_total, ROWCAP);
  }
}

// Static conflict scheduling: one block per batch of 256 consecutive rows.
// Row r's vertex set = {r} U nbr_up(r). In claim-round k a pending row wins iff
// it holds the min key on all its vertices (epoch-keyed: newer rounds always
// beat stale keys). >=1 retire per round (global min-rank pending row always
// wins), so k <= 256. depth[b] = final k = max round in batch.
// Also initializes minidx[] (stream-ordered before k_fold1).
__global__ __launch_bounds__(256) void k_sched(const uint16_t* __restrict__ edges,
    const uint32_t* __restrict__ cnt, uint16_t* __restrict__ sched,
    int* __restrict__ depth, uint32_t* __restrict__ minidx) {
  __shared__ uint32_t claim[NDET];     // 32 KB
  __shared__ int nleft;
  const int t = threadIdx.x;
  const int base = blockIdx.x << 8;
  const int r = base + t;
  minidx[r] = 0xFFFFFFFFu;
  {
    uint4* c4 = reinterpret_cast<uint4*>(claim);
    uint4 ff = make_uint4(0xFFFFFFFFu, 0xFFFFFFFFu, 0xFFFFFFFFu, 0xFFFFFFFFu);
    for (int v = t; v < NDET / 4; v += 256) c4[v] = ff;
  }
  const uint16_t* ep = edges + (size_t)r * ROWCAP;
  uint4 pa = *reinterpret_cast<const uint4*>(ep);
  uint4 pb = *reinterpret_cast<const uint4*>(ep + 8);
  uint32_t deg = cnt[r];
  if (t == 0) nleft = 0;
  __syncthreads();
  bool done = (deg == 0u);             // zero-deg rows are exact no-ops, round 0
  if (!done) atomicAdd(&nleft, 1);
  uint32_t myround = 0u;
  int k = 0;
  __syncthreads();                     // nleft final; uniform reads below

  while (nleft > 0) {                  // uniform (read after barrier each iter)
    ++k;
    const uint32_t key = ((uint32_t)(600 - k) << 9) | (uint32_t)t;  // newer round -> smaller
    if (!done) {
      atomicMin(&claim[r], key);
      #pragma unroll
      for (int e = 0; e < 8; ++e)
        if (e < (int)deg) atomicMin(&claim[EDGE(e)], key);
      if (deg > 8u) {
        #pragma unroll
        for (int e = 8; e < 16; ++e)
          if (e < (int)deg) atomicMin(&claim[EDGE(e)], key);
      }
      if (deg > 16u)
        for (int e = 16; e < (int)deg; ++e) atomicMin(&claim[(int)ep[e]], key);
    }
    __syncthreads();
    if (!done) {
      bool ready = (claim[r] == key);
      #pragma unroll
      for (int e = 0; e < 8; ++e)
        if (e < (int)deg && claim[EDGE(e)] != key) ready = false;
      if (ready && deg > 8u) {
        #pragma unroll
        for (int e = 8; e < 16; ++e)
          if (e < (int)deg && claim[EDGE(e)] != key) ready = false;
      }
      if (ready && deg > 16u)
        for (int e = 16; ready && e < (int)deg; ++e)
          if (claim[(int)ep[e]] != key) ready = false;
      if (ready) { myround = (uint32_t)k; done = true; atomicSub(&nleft, 1); }
    }
    __syncthreads();                   // retires visible; round-k keys now stale
  }
  sched[r] = (uint16_t)myround;
  if (t == 0) depth[blockIdx.x] = k;
}

// Multi-wave sequential-semantics executor: 32 batches of 256 rows in order;
// within a batch, rows execute at their precomputed round (disjoint per round).
// Uniform for-k loop (depth precomputed) -> barrier-safe across 4 waves.
__global__ __launch_bounds__(256) void k_scan(const uint16_t* __restrict__ edges,
    const uint32_t* __restrict__ cnt, const uint16_t* __restrict__ sched,
    const int* __restrict__ depth, uint32_t* __restrict__ aout) {
  __shared__ uint16_t a[NDET];         // 16 KB labels
  const int t = threadIdx.x;
  for (int v = t; v < NDET; v += 256) a[v] = (uint16_t)v;

  // prefetch batch 0 (one row per thread)
  const uint16_t* ep = edges + (size_t)t * ROWCAP;
  uint4 pa = *reinterpret_cast<const uint4*>(ep);
  uint4 pb = *reinterpret_cast<const uint4*>(ep + 8);
  uint32_t deg = cnt[t];
  uint32_t rnd = sched[t];
  int dep = depth[0];
  __syncthreads();

  for (int b = 0; b < NBATCH; ++b) {
    const int r = (b << 8) + t;
    uint4 pan = make_uint4(0, 0, 0, 0), pbn = make_uint4(0, 0, 0, 0);
    uint32_t degn = 0u, rndn = 0u;
    int depn = 0;
    if (b < NBATCH - 1) {              // prefetch next batch; waits land after rounds
      const uint16_t* en = edges + (size_t)(r + BATCH) * ROWCAP;
      pan = *reinterpret_cast<const uint4*>(en);
      pbn = *reinterpret_cast<const uint4*>(en + 8);
      degn = cnt[r + BATCH];
      rndn = sched[r + BATCH];
      depn = depth[b + 1];
    }
    for (int k = 1; k <= dep; ++k) {   // uniform loop; no ballot
      if (rnd == (uint32_t)k) {
        // exact row semantics: prefix-min chain over ascending neighbors
        int cur = (int)a[r];
        #pragma unroll
        for (int e = 0; e < 8; ++e) {
          if (e < (int)deg) {
            int j = EDGE(e);
            int aj = (int)a[j];
            if (aj < cur) cur = aj;
            a[j] = (uint16_t)cur;
          }
        }
        if (deg > 8u) {
          #pragma unroll
          for (int e = 8; e < 16; ++e) {
            if (e < (int)deg) {
              int j = EDGE(e);
              int aj = (int)a[j];
              if (aj < cur) cur = aj;
              a[j] = (uint16_t)cur;
            }
          }
        }
        if (deg > 16u) {
          for (int e = 16; e < (int)deg; ++e) {
            int j = (int)edges[(size_t)r * ROWCAP + e];
            int aj = (int)a[j];
            if (aj < cur) cur = aj;
            a[j] = (uint16_t)cur;
          }
        }
        a[r] = (uint16_t)cur;
      }
      __syncthreads();
    }
    pa = pan; pb = pbn; deg = degn; rnd = rndn; dep = depn;
  }

  __syncthreads();
  for (int v = t; v < NDET; v += 256) aout[v] = (uint32_t)a[v];
}

// per-label stats: count, min member index, argmax-conf (min-idx tie-break)
__global__ __launch_bounds__(256) void k_fold1(const uint32_t* __restrict__ alab,
    const float* __restrict__ conf, unsigned long long* __restrict__ mcg,
    uint32_t* __restrict__ cntk, uint32_t* __restrict__ minidx) {
  int v = blockIdx.x * 256 + threadIdx.x;
  if (v >= NDET) return;
  uint32_t L = alab[v];
  unsigned long long key = ((unsigned long long)__float_as_uint(conf[v]) << 32)
                         | (unsigned long long)(NDET - 1 - v);
  atomicMax(&mcg[L], key);
  atomicAdd(&cntk[L], 1u);
  atomicMin(&minidx[L], (uint32_t)v);
}

// rank of argmax member within its cluster = #members with smaller index
__global__ __launch_bounds__(256) void k_fold2(const uint32_t* __restrict__ alab,
    const unsigned long long* __restrict__ mcg, uint32_t* __restrict__ rankk) {
  int v = blockIdx.x * 256 + threadIdx.x;
  if (v >= NDET) return;
  uint32_t L = alab[v];
  uint32_t g = (uint32_t)(NDET - 1) - (uint32_t)(mcg[L] & 0xFFFFFFFFull);
  if ((uint32_t)v < g) atomicAdd(&rankk[L], 1u);
}

// Emit one mask bit per PRESENT label value (cntk[L] > 0). No root assumption:
// a label L can be held by vertices even when a[L] != L (one-pass prefix-min
// scan is not a full connected-components pass).
__global__ __launch_bounds__(256) void k_mask(const uint32_t* __restrict__ cntk,
    const uint32_t* __restrict__ minidx, const uint32_t* __restrict__ rankk,
    int32_t* __restrict__ out) {
  int L = blockIdx.x * 256 + threadIdx.x;
  if (L >= NDET) return;
  uint32_t c = cntk[L];
  if (c > 0u) {
    uint32_t idx = (c == 1u) ? minidx[L] : rankk[L];
    out[idx] = 1;                      // idx < NDET always (member index or rank < count)
  }
}

extern "C" void kernel_launch(void* const* d_in, const int* in_sizes, int n_in,
                              void* d_out, int out_size, void* d_ws, size_t ws_size,
                              hipStream_t stream) {
  const float4* bb  = (const float4*)d_in[0];
  const float* conf = (const float*)d_in[1];
  char* ws = (char*)d_ws;
  float4*             boxes  = (float4*)(ws + 0);
  float*              area   = (float*)(ws + 131072);
  uint32_t*           minidx = (uint32_t*)(ws + 131072);  // reuses area (dead after k_edges)
  uint32_t*           cnt    = (uint32_t*)(ws + 163840);
  uint32_t*           alab   = (uint32_t*)(ws + 196608);
  unsigned long long* mcg    = (unsigned long long*)(ws + 229376);
  uint32_t*           cntk   = (uint32_t*)(ws + 294912);
  uint32_t*           rankk  = (uint32_t*)(ws + 327680);
  uint16_t*           sched  = (uint16_t*)(ws + 360448);
  int*                depth  = (int*)(ws + 376832);
  uint16_t*           edges  = (uint16_t*)(ws + 393216);
  int32_t* out = (int32_t*)d_out;

  hipLaunchKernelGGL(k_init,  dim3(NDET / 256), dim3(256), 0, stream,
                     bb, boxes, area, mcg, cntk, rankk, out);
  hipLaunchKernelGGL(k_edges, dim3(1024),       dim3(256), 0, stream,
                     boxes, area, cnt, edges);
  hipLaunchKernelGGL(k_sched, dim3(NBATCH),     dim3(256), 0, stream,
                     edges, cnt, sched, depth, minidx);
  hipLaunchKernelGGL(k_scan,  dim3(1),          dim3(256), 0, stream,
                     edges, cnt, sched, depth, alab);
  hipLaunchKernelGGL(k_fold1, dim3(NDET / 256), dim3(256), 0, stream,
                     alab, conf, mcg, cntk, minidx);
  hipLaunchKernelGGL(k_fold2, dim3(NDET / 256), dim3(256), 0, stream,
                     alab, mcg, rankk);
  hipLaunchKernelGGL(k_mask,  dim3(NDET / 256), dim3(256), 0, stream,
                     cntk, minidx, rankk, out);
}

// Round 9
// 333.163 us; speedup vs baseline: 1.4611x; 1.0513x over previous
//
#include <hip/hip_runtime.h>
#include <stdint.h>

#define NDET 8192
#define ROWCAP 128      // max stored edges per row (j>i). P(overflow) ~ 0 for this data.
#define BATCH 256
#define NBATCH (NDET / BATCH)

// ---------------- ws layout (bytes) ----------------
// 0        u32    cnt   [8192]    32768
// 32768    u32    alab  [8192]    32768
// 65536    u64    mcg   [8192]    65536
// 131072   u32    cntk  [8192]    32768
// 163840   u32    rankk [8192]    32768
// 196608   u32    minidx[8192]    32768
// 229376   u16    sched [8192]    16384
// 245760   int    depth [32]        128
// 262144   u16    edges[8192][128] 2097152   (total 2359296 B)

// Extract edge e (compile-time constant after unroll) from the two uint4 regs.
#define EW(e) ((e) < 8 ? (((e) >> 1) == 0 ? pa.x : ((e) >> 1) == 1 ? pa.y : ((e) >> 1) == 2 ? pa.z : pa.w) \
                       : ((((e) - 8) >> 1) == 0 ? pb.x : (((e) - 8) >> 1) == 1 ? pb.y : (((e) - 8) >> 1) == 2 ? pb.z : pb.w))
#define EDGE(e) ((int)((EW(e) >> (((e) & 1) * 16)) & 0xFFFFu))

// Corner-form + area computed on the fly from raw cxcywh (bit-identical to the
// reference expressions; contract off so no FMA fusion changes rounding).
__device__ __forceinline__ void box_corners(const float4 b, float& x1, float& y1,
                                            float& x2, float& y2, float& ar) {
  #pragma clang fp contract(off)
  x1 = b.x - 0.5f * b.z; y1 = b.y - 0.5f * b.w;
  x2 = b.x + 0.5f * b.z; y2 = b.y + 0.5f * b.w;
  ar = (x2 - x1) * (y2 - y1);
}

// One wave handles rows (w) and (8191-w): balanced upper-triangle scan.
__global__ __launch_bounds__(256) void k_edges(const float4* __restrict__ bb,
    uint32_t* __restrict__ cnt, uint16_t* __restrict__ edges) {
  #pragma clang fp contract(off)
  int wid  = (blockIdx.x * 256 + threadIdx.x) >> 6;   // 0..4095
  int lane = threadIdx.x & 63;
  for (int half = 0; half < 2; ++half) {
    int r = (half == 0) ? wid : (NDET - 1 - wid);
    float ix1, iy1, ix2, iy2, ai;
    box_corners(bb[r], ix1, iy1, ix2, iy2, ai);
    uint16_t* erow = edges + (size_t)r * ROWCAP;
    int cnt_total = 0;
    for (int jc = (r + 1) >> 6; jc < NDET / 64; ++jc) {
      int j = (jc << 6) + lane;
      bool pred = false;
      if (j > r) {
        float jx1, jy1, jx2, jy2, aj;
        box_corners(bb[j], jx1, jy1, jx2, jy2, aj);
        float ltx = fmaxf(ix1, jx1), lty = fmaxf(iy1, jy1);
        float rbx = fminf(ix2, jx2), rby = fminf(iy2, jy2);
        float iw = fmaxf(rbx - ltx, 0.0f), ih = fmaxf(rby - lty, 0.0f);
        float inter = iw * ih;
        float uni = ai + aj - inter;     // > 0 always (w,h >= 10)
        float iou = inter / uni;         // IEEE div, matches reference
        pred = iou > 0.1f;
      }
      unsigned long long m = __ballot(pred);
      if (pred) {
        int pos = cnt_total + __popcll(m & ((1ull << lane) - 1ull));
        if (pos < ROWCAP) erow[pos] = (uint16_t)j;
      }
      cnt_total += __popcll(m);
    }
    if (lane == 0) cnt[r] = (uint32_t)min(cnt_total, ROWCAP);
  }
}

// Static conflict scheduling: one block per batch of 256 consecutive rows.
// Epoch-keyed claims (newer round -> smaller key), >=1 retire/round => k<=256.
// Also zero-inits the per-label stat tables (consumed by k_post later).
__global__ __launch_bounds__(256) void k_sched(const uint16_t* __restrict__ edges,
    const uint32_t* __restrict__ cnt, uint16_t* __restrict__ sched,
    int* __restrict__ depth, uint32_t* __restrict__ minidx,
    unsigned long long* __restrict__ mcg, uint32_t* __restrict__ cntk,
    uint32_t* __restrict__ rankk) {
  __shared__ uint32_t claim[NDET];     // 32 KB
  __shared__ int nleft;
  const int t = threadIdx.x;
  const int base = blockIdx.x << 8;
  const int r = base + t;
  minidx[r] = 0xFFFFFFFFu;
  mcg[r] = 0ull; cntk[r] = 0u; rankk[r] = 0u;
  {
    uint4* c4 = reinterpret_cast<uint4*>(claim);
    uint4 ff = make_uint4(0xFFFFFFFFu, 0xFFFFFFFFu, 0xFFFFFFFFu, 0xFFFFFFFFu);
    for (int v = t; v < NDET / 4; v += 256) c4[v] = ff;
  }
  const uint16_t* ep = edges + (size_t)r * ROWCAP;
  uint4 pa = *reinterpret_cast<const uint4*>(ep);
  uint4 pb = *reinterpret_cast<const uint4*>(ep + 8);
  uint32_t deg = cnt[r];
  int js[16];
  #pragma unroll
  for (int e = 0; e < 16; ++e) js[e] = EDGE(e);
  if (t == 0) nleft = 0;
  __syncthreads();
  bool done = (deg == 0u);             // zero-deg rows are exact no-ops, round 0
  if (!done) atomicAdd(&nleft, 1);
  uint32_t myround = 0u;
  int k = 0;
  __syncthreads();                     // nleft final; uniform reads below

  while (nleft > 0) {                  // uniform (read after barrier each iter)
    ++k;
    const uint32_t key = ((uint32_t)(600 - k) << 9) | (uint32_t)t;  // newer round -> smaller
    if (!done) {
      atomicMin(&claim[r], key);
      #pragma unroll
      for (int e = 0; e < 16; ++e)
        if (e < (int)deg) atomicMin(&claim[js[e]], key);
      if (deg > 16u)
        for (int e = 16; e < (int)deg; ++e) atomicMin(&claim[(int)ep[e]], key);
    }
    __syncthreads();
    if (!done) {
      uint32_t cl[16];
      #pragma unroll
      for (int e = 0; e < 16; ++e)
        cl[e] = (e < (int)deg) ? claim[js[e]] : key;   // independent reads, one wait
      bool ready = (claim[r] == key);
      #pragma unroll
      for (int e = 0; e < 16; ++e)
        if (cl[e] != key) ready = false;
      if (ready && deg > 16u)
        for (int e = 16; ready && e < (int)deg; ++e)
          if (claim[(int)ep[e]] != key) ready = false;
      if (ready) { myround = (uint32_t)k; done = true; atomicSub(&nleft, 1); }
    }
    __syncthreads();                   // retires visible; round-k keys now stale
  }
  sched[r] = (uint16_t)myround;
  if (t == 0) depth[blockIdx.x] = k;
}

// Multi-wave sequential-semantics executor: 32 batches of 256 rows in order;
// within a batch, rows execute at their precomputed round (disjoint per round).
// Row body = 3 phases (read-all / reg prefix-min / write-all): neighbors are
// strictly ascending => distinct, and the reference reads pre-row values, so
// this is exact and removes the per-edge LDS RAW round-trip serialization.
__global__ __launch_bounds__(256) void k_scan(const uint16_t* __restrict__ edges,
    const uint32_t* __restrict__ cnt, const uint16_t* __restrict__ sched,
    const int* __restrict__ depth, uint32_t* __restrict__ aout) {
  __shared__ uint16_t a[NDET];         // 16 KB labels
  const int t = threadIdx.x;
  for (int v = t; v < NDET; v += 256) a[v] = (uint16_t)v;

  // prefetch batch 0 (one row per thread)
  const uint16_t* ep = edges + (size_t)t * ROWCAP;
  uint4 pa = *reinterpret_cast<const uint4*>(ep);
  uint4 pb = *reinterpret_cast<const uint4*>(ep + 8);
  uint32_t deg = cnt[t];
  uint32_t rnd = sched[t];
  int dep = depth[0];
  __syncthreads();

  for (int b = 0; b < NBATCH; ++b) {
    const int r = (b << 8) + t;
    uint4 pan = make_uint4(0, 0, 0, 0), pbn = make_uint4(0, 0, 0, 0);
    uint32_t degn = 0u, rndn = 0u;
    int depn = 0;
    if (b < NBATCH - 1) {              // prefetch next batch; waits land after rounds
      const uint16_t* en = edges + (size_t)(r + BATCH) * ROWCAP;
      pan = *reinterpret_cast<const uint4*>(en);
      pbn = *reinterpret_cast<const uint4*>(en + 8);
      degn = cnt[r + BATCH];
      rndn = sched[r + BATCH];
      depn = depth[b + 1];
    }
    for (int k = 1; k <= dep; ++k) {   // uniform loop; no ballot
      if (rnd == (uint32_t)k) {
        int js[16], ls[16];
        #pragma unroll
        for (int e = 0; e < 16; ++e) js[e] = EDGE(e);
        #pragma unroll
        for (int e = 0; e < 16; ++e)   // phase 1: independent reads, one wait
          ls[e] = (e < (int)deg) ? (int)a[js[e]] : 0x7FFFFFFF;
        int cur = (int)a[r];
        #pragma unroll
        for (int e = 0; e < 16; ++e) { // phase 2: register prefix-min
          if (ls[e] < cur) cur = ls[e];
          ls[e] = cur;
        }
        #pragma unroll
        for (int e = 0; e < 16; ++e)   // phase 3: independent writes
          if (e < (int)deg) a[js[e]] = (uint16_t)ls[e];
        if (deg > 16u) {               // rare tail: sequential exact
          for (int e = 16; e < (int)deg; ++e) {
            int j = (int)edges[(size_t)r * ROWCAP + e];
            int aj = (int)a[j];
            if (aj < cur) cur = aj;
            a[j] = (uint16_t)cur;
          }
        }
        a[r] = (uint16_t)cur;
      }
      __syncthreads();
    }
    pa = pan; pb = pbn; deg = degn; rnd = rndn; dep = depn;
  }

  __syncthreads();
  for (int v = t; v < NDET; v += 256) aout[v] = (uint32_t)a[v];
}

// Fused per-label fold + mask: single block (single CU/XCD), phases separated
// by __syncthreads + fence; each table is first-read only after its write phase.
__global__ __launch_bounds__(1024) void k_post(const uint32_t* __restrict__ alab,
    const float* __restrict__ conf, unsigned long long* __restrict__ mcg,
    uint32_t* __restrict__ cntk, uint32_t* __restrict__ rankk,
    uint32_t* __restrict__ minidx, int32_t* __restrict__ out) {
  const int t = threadIdx.x;
  for (int v = t; v < NDET; v += 1024) out[v] = 0;   // zero output mask
  // phase A: count, min member index, argmax-conf (min-idx tie-break)
  for (int v = t; v < NDET; v += 1024) {
    uint32_t L = alab[v];
    unsigned long long key = ((unsigned long long)__float_as_uint(conf[v]) << 32)
                           | (unsigned long long)(NDET - 1 - v);
    atomicMax(&mcg[L], key);
    atomicAdd(&cntk[L], 1u);
    atomicMin(&minidx[L], (uint32_t)v);
  }
  __syncthreads(); __threadfence();
  // phase B: rank of the argmax member = #members with smaller index
  for (int v = t; v < NDET; v += 1024) {
    uint32_t L = alab[v];
    uint32_t g = (uint32_t)(NDET - 1) - (uint32_t)(mcg[L] & 0xFFFFFFFFull);
    if ((uint32_t)v < g) atomicAdd(&rankk[L], 1u);
  }
  __syncthreads(); __threadfence();
  // phase C: one mask bit per present label value
  for (int L = t; L < NDET; L += 1024) {
    uint32_t c = cntk[L];
    if (c > 0u) {
      uint32_t idx = (c == 1u) ? minidx[L] : rankk[L];
      out[idx] = 1;                    // idx < NDET always
    }
  }
}

extern "C" void kernel_launch(void* const* d_in, const int* in_sizes, int n_in,
                              void* d_out, int out_size, void* d_ws, size_t ws_size,
                              hipStream_t stream) {
  const float4* bb  = (const float4*)d_in[0];
  const float* conf = (const float*)d_in[1];
  char* ws = (char*)d_ws;
  uint32_t*           cnt    = (uint32_t*)(ws + 0);
  uint32_t*           alab   = (uint32_t*)(ws + 32768);
  unsigned long long* mcg    = (unsigned long long*)(ws + 65536);
  uint32_t*           cntk   = (uint32_t*)(ws + 131072);
  uint32_t*           rankk  = (uint32_t*)(ws + 163840);
  uint32_t*           minidx = (uint32_t*)(ws + 196608);
  uint16_t*           sched  = (uint16_t*)(ws + 229376);
  int*                depth  = (int*)(ws + 245760);
  uint16_t*           edges  = (uint16_t*)(ws + 262144);
  int32_t* out = (int32_t*)d_out;

  hipLaunchKernelGGL(k_edges, dim3(1024),   dim3(256),  0, stream,
                     bb, cnt, edges);
  hipLaunchKernelGGL(k_sched, dim3(NBATCH), dim3(256),  0, stream,
                     edges, cnt, sched, depth, minidx, mcg, cntk, rankk);
  hipLaunchKernelGGL(k_scan,  dim3(1),      dim3(256),  0, stream,
                     edges, cnt, sched, depth, alab);
  hipLaunchKernelGGL(k_post,  dim3(1),      dim3(1024), 0, stream,
                     alab, conf, mcg, cntk, rankk, minidx, out);
}